// Round 18
// baseline (530.983 us; speedup 1.0000x reference)
//
#include <hip/hip_runtime.h>
#include <hip/hip_bf16.h>
#include <cstdint>
#include <cstddef>

// GraphAttentionLayer: N=30000, E=480000, C=128, H=8, DH=16, NB=32, NA=16, FC=64.
//
// R18 vs R17 (309us msg_attn; barrier reduction null; occupancy pinned at 44%
// purely by LDS 35840B x 4 blocks):
//   TILE 64 -> 32: every LDS region halves -> 17920 B/block -> 8 blocks/CU
//   (32 waves = occupancy cap; VGPR 60 supports 8 waves/SIMD).
//   launch_bounds(256,8), grid 15000. Per-edge MFMA unchanged (m-frags 4->2);
//   cost: 2x per-edge Wct/Wvt L2 traffic (~28us total) + 2x barriers (cheap).
//   aggregate_k: 4-deep unroll.
// Structure = R16 column-split phases (R17's wave-local MLP gave nothing).

typedef unsigned short u16;
typedef unsigned int u32;
typedef __attribute__((ext_vector_type(8))) short bf16x8;
typedef __attribute__((ext_vector_type(4))) float f32x4;

union fu_ { float f; u32 u; };
static __device__ __forceinline__ float lo2f(u32 v) { fu_ x; x.u = v << 16; return x.f; }
static __device__ __forceinline__ float hi2f(u32 v) { fu_ x; x.u = v & 0xFFFF0000u; return x.f; }
static __device__ __forceinline__ u16 f2bf(float f) {
    union { __hip_bfloat16 h; u16 u; } c;
    c.h = __float2bfloat16(f);
    return c.u;
}
static __device__ __forceinline__ u32 pack2(float a, float b) {
    return (u32)f2bf(a) | ((u32)f2bf(b) << 16);
}
static __device__ __forceinline__ float sigmoidf_(float x) { return 1.0f / (1.0f + __expf(-x)); }
static __device__ __forceinline__ float siluf_(float x)    { return x * sigmoidf_(x); }
static __device__ __forceinline__ float slreluf_(float x)  { return x * (0.2f + 0.8f * sigmoidf_(x)); }

#define MFMA16(a, b, c) __builtin_amdgcn_mfma_f32_16x16x32_bf16((a), (b), (c), 0, 0, 0)

static __device__ __forceinline__ bf16x8 ld8f_bf(const float* __restrict__ p) {
    const float4 x = *reinterpret_cast<const float4*>(p);
    const float4 y = *reinterpret_cast<const float4*>(p + 4);
    bf16x8 r;
    r[0] = (short)f2bf(x.x); r[1] = (short)f2bf(x.y);
    r[2] = (short)f2bf(x.z); r[3] = (short)f2bf(x.w);
    r[4] = (short)f2bf(y.x); r[5] = (short)f2bf(y.y);
    r[6] = (short)f2bf(y.z); r[7] = (short)f2bf(y.w);
    return r;
}

// bijective XCD swizzle (m204)
static __device__ __forceinline__ int xcd_swz(int orig, int nwg) {
    const int q = nwg >> 3, rr = nwg & 7;
    const int xcd = orig & 7, idx = orig >> 3;
    return (xcd < rr ? xcd * (q + 1) : rr * (q + 1) + (xcd - rr) * q) + idx;
}

// ---------------- CSR build ----------------
__global__ void hist_k(const int* __restrict__ dst, int* __restrict__ deg, int E) {
    int i = blockIdx.x * blockDim.x + threadIdx.x;
    if (i < E) atomicAdd(&deg[dst[i]], 1);
}

__global__ void scan_k(const int* __restrict__ deg, int* __restrict__ rowptr,
                       int* __restrict__ cursor, int n) {
    __shared__ int part[1024];
    const int t = threadIdx.x;
    const int C = (n + 1023) / 1024;
    const int lo = t * C;
    const int hi = (lo + C < n) ? (lo + C) : n;
    int s = 0;
    for (int i = lo; i < hi; ++i) s += deg[i];
    part[t] = s;
    __syncthreads();
    for (int off = 1; off < 1024; off <<= 1) {
        int v = part[t];
        int u = (t >= off) ? part[t - off] : 0;
        __syncthreads();
        part[t] = v + u;
        __syncthreads();
    }
    int excl = (t == 0) ? 0 : part[t - 1];
    for (int i = lo; i < hi; ++i) {
        rowptr[i] = excl;
        cursor[i] = excl;
        excl += deg[i];
    }
    if (t == 1023) rowptr[n] = part[1023];
}

__global__ void fill_k(const int* __restrict__ dst, int* __restrict__ cursor,
                       int* __restrict__ eids, int E) {
    int i = blockIdx.x * blockDim.x + threadIdx.x;
    if (i < E) {
        int d = dst[i];
        int p = atomicAdd(&cursor[d], 1);
        eids[p] = i;
    }
}

// ---------------- weight prep (all transposed, bf16) ----------------
__global__ void prep_w_k(const float* __restrict__ Wa, const float* __restrict__ Wl,
                         const float* __restrict__ Wv,
                         const float* __restrict__ W1, const float* __restrict__ W2,
                         const float* __restrict__ W3,
                         const float* __restrict__ Wsrc, const float* __restrict__ Wdst,
                         const float* __restrict__ Wout,
                         u16* __restrict__ Wct, u16* __restrict__ Wvt,
                         u16* __restrict__ Bt1, u16* __restrict__ Bt2,
                         u16* __restrict__ Bt3,
                         u16* __restrict__ Wst, u16* __restrict__ Wdt,
                         u16* __restrict__ Wot) {
    int idx = blockIdx.x * 256 + threadIdx.x;
    if (idx < 32768) {
        int c = idx >> 7, k = idx & 127;
        float v = (c < 128) ? Wa[(size_t)k * 128 + c] : Wl[(size_t)k * 128 + (c - 128)];
        Wct[idx] = f2bf(v);
    } else if (idx < 49152) {
        int t = idx - 32768;
        int j = t >> 7, c = t & 127;
        Wvt[t] = f2bf(Wv[(size_t)c * 128 + j]);
    } else if (idx < 53248) {
        int t = idx - 49152;
        int c = t >> 6, k = t & 63;
        Bt1[t] = f2bf(W1[(size_t)k * 64 + c]);
    } else if (idx < 57344) {
        int t = idx - 53248;
        int c = t >> 6, k = t & 63;
        Bt2[t] = f2bf(W2[(size_t)k * 64 + c]);
    } else if (idx < 65536) {
        int t = idx - 57344;
        int c = t >> 6, k = t & 63;
        Bt3[t] = f2bf(W3[(size_t)k * 128 + c]);
    } else if (idx < 81920) {
        int t = idx - 65536;
        int c = t >> 7, k = t & 127;
        Wst[t] = f2bf(Wsrc[(size_t)k * 128 + c]);
    } else if (idx < 98304) {
        int t = idx - 81920;
        int c = t >> 7, k = t & 127;
        Wdt[t] = f2bf(Wdst[(size_t)k * 128 + c]);
    } else if (idx < 114688) {
        int t = idx - 98304;
        int c = t >> 7, k = t & 127;
        Wot[t] = f2bf(Wout[(size_t)k * 128 + c]);
    }
}

// ---------------- dual node projection: Psrc,Pdst (bf16 out) in one pass ----------------
__global__ __launch_bounds__(256) void proj2_mfma_k(const float* __restrict__ A,
                                                    const u16* __restrict__ Wt1,
                                                    const u16* __restrict__ Wt2,
                                                    const float* __restrict__ bias1,
                                                    u16* __restrict__ O1,
                                                    u16* __restrict__ O2, int M) {
    const int tid  = threadIdx.x;
    const int lane = tid & 63;
    const int w    = tid >> 6;
    const int lr   = lane & 15;
    const int lg   = lane >> 4;
    const int e0   = blockIdx.x * 64;

    f32x4 acc1[4][2], acc2[4][2];
#pragma unroll
    for (int m = 0; m < 4; ++m)
#pragma unroll
        for (int n = 0; n < 2; ++n) { acc1[m][n] = (f32x4)(0.0f); acc2[m][n] = (f32x4)(0.0f); }

#pragma unroll
    for (int ks = 0; ks < 4; ++ks) {
        const int kk = lg * 8 + ks * 32;
        bf16x8 a[4], b1v[2], b2v[2];
#pragma unroll
        for (int m = 0; m < 4; ++m) {
            int row = e0 + lr + 16 * m;
            row = (row < M) ? row : (M - 1);
            a[m] = ld8f_bf(&A[(size_t)row * 128 + kk]);
        }
#pragma unroll
        for (int n = 0; n < 2; ++n) {
            const int c = 32 * w + 16 * n + lr;
            b1v[n] = *reinterpret_cast<const bf16x8*>(&Wt1[(size_t)c * 128 + kk]);
            b2v[n] = *reinterpret_cast<const bf16x8*>(&Wt2[(size_t)c * 128 + kk]);
        }
#pragma unroll
        for (int m = 0; m < 4; ++m)
#pragma unroll
            for (int n = 0; n < 2; ++n) {
                acc1[m][n] = MFMA16(a[m], b1v[n], acc1[m][n]);
                acc2[m][n] = MFMA16(a[m], b2v[n], acc2[m][n]);
            }
    }

#pragma unroll
    for (int n = 0; n < 2; ++n) {
        const int j = 32 * w + 16 * n + lr;
        const float bv = bias1[j];
#pragma unroll
        for (int m = 0; m < 4; ++m)
#pragma unroll
            for (int i = 0; i < 4; ++i) {
                const int row = e0 + 16 * m + 4 * lg + i;
                if (row < M) {
                    O1[(size_t)row * 128 + j] = f2bf(acc1[m][n][i] + bv);
                    O2[(size_t)row * 128 + j] = f2bf(acc2[m][n][i]);
                }
            }
    }
}

// ---------------- fused radial MLP + message + attention + value ----------------
// TILE=32 edges; LDS 17920 B -> 8 blocks/CU; column-split phases (R16 structure).
__global__ __launch_bounds__(256, 8) void msg_attn_k(
    const float* __restrict__ eemb, const float* __restrict__ nattr,
    const float* __restrict__ ea,
    const int* __restrict__ src, const int* __restrict__ dst,
    const int* __restrict__ eids,
    const u16* __restrict__ Bt1, const float* __restrict__ b1,
    const u16* __restrict__ Bt2, const float* __restrict__ b2,
    const u16* __restrict__ Bt3,
    const u16* __restrict__ Ps, const u16* __restrict__ Pd,
    const u16* __restrict__ Wct, const u16* __restrict__ Wvt,
    const float* __restrict__ att_dot, const float* __restrict__ w_int,
    float* __restrict__ LG, u16* __restrict__ V, int E) {
    __shared__ __align__(16) char smem[17920];
    char* regA   = smem;                    // H1 [0,4K) + H2 [4K,8K); later V1s (8K)
    char* regB   = smem + 8192;             // Wts -> MSG (in place) -> Vout (8K)
    float* lgs   = (float*)(smem + 16384);  // 32*8 f32 = 1K
    int*   eid_l = (int*)(smem + 17408);    // [32]
    int*   src_l = eid_l + 32;
    int*   dst_l = src_l + 32;
    float* ea_l  = (float*)(dst_l + 32);    // [32]

    const int tid  = threadIdx.x;
    const int lane = tid & 63;
    const int w    = tid >> 6;
    const int lr   = lane & 15;
    const int lg   = lane >> 4;
    const int e0   = xcd_swz(blockIdx.x, gridDim.x) * 32;  // CSR slot base

    // ---- phase 0: stage slot->edge metadata ----
    if (tid < 32) {
        int slot = e0 + tid;
        int e = (slot < E) ? eids[slot] : eids[E - 1];
        eid_l[tid] = e;
        src_l[tid] = src[e];
        dst_l[tid] = dst[e];
        ea_l[tid]  = ea[e];
    }
    __syncthreads();

    // ---- phase 1: fc1  H1 = silu(WF @ W1 + b1), A gathered via eid ----
    {
        f32x4 acc1[2];
#pragma unroll
        for (int m = 0; m < 2; ++m) acc1[m] = (f32x4)(0.0f);
#pragma unroll
        for (int ks = 0; ks < 2; ++ks) {
            const int kk = lg * 8 + ks * 32;
            bf16x8 a[2];
#pragma unroll
            for (int m = 0; m < 2; ++m) {
                const int r = lr + 16 * m;
                const float* ap;
                if (kk < 32)      ap = &eemb[(size_t)eid_l[r] * 32 + kk];
                else if (kk < 48) ap = &nattr[(size_t)src_l[r] * 16 + (kk - 32)];
                else              ap = &nattr[(size_t)dst_l[r] * 16 + (kk - 48)];
                a[m] = ld8f_bf(ap);
            }
            const bf16x8 b = *reinterpret_cast<const bf16x8*>(&Bt1[(size_t)(16 * w + lr) * 64 + kk]);
#pragma unroll
            for (int m = 0; m < 2; ++m) acc1[m] = MFMA16(a[m], b, acc1[m]);
        }
        const int c = 16 * w + lr;
        const float bias = b1[c];
#pragma unroll
        for (int m = 0; m < 2; ++m)
#pragma unroll
            for (int i = 0; i < 4; ++i) {
                const int r = 16 * m + 4 * lg + i;
                const int byte = (r * 128 + c * 2) ^ ((r & 7) << 4);
                *reinterpret_cast<u16*>(regA + byte) = f2bf(siluf_(acc1[m][i] + bias));
            }
    }
    __syncthreads();

    // ---- phase 2: fc2  H2 = silu(H1 @ W2 + b2) ----
    {
        f32x4 acc2[2];
#pragma unroll
        for (int m = 0; m < 2; ++m) acc2[m] = (f32x4)(0.0f);
#pragma unroll
        for (int ks = 0; ks < 2; ++ks) {
            const int kk = lg * 8 + ks * 32;
            bf16x8 a[2];
#pragma unroll
            for (int m = 0; m < 2; ++m) {
                const int r = lr + 16 * m;
                const int byte = (r * 128 + kk * 2) ^ ((r & 7) << 4);
                a[m] = *reinterpret_cast<const bf16x8*>(regA + byte);
            }
            const bf16x8 b = *reinterpret_cast<const bf16x8*>(&Bt2[(size_t)(16 * w + lr) * 64 + kk]);
#pragma unroll
            for (int m = 0; m < 2; ++m) acc2[m] = MFMA16(a[m], b, acc2[m]);
        }
        const int c = 16 * w + lr;
        const float bias = b2[c];
#pragma unroll
        for (int m = 0; m < 2; ++m)
#pragma unroll
            for (int i = 0; i < 4; ++i) {
                const int r = 16 * m + 4 * lg + i;
                const int byte = (r * 128 + c * 2) ^ ((r & 7) << 4);
                *reinterpret_cast<u16*>(regA + 4096 + byte) = f2bf(siluf_(acc2[m][i] + bias));
            }
    }
    __syncthreads();

    // ---- prefetch (short range): epilogue Ps/Pd, consumed in phase 4 ----
    uint4 psv_r[2], pdv_r[2];
    {
        const int c8p = (tid & 15) * 8;
#pragma unroll
        for (int t = 0; t < 2; ++t) {
            const int r = (tid >> 4) + 16 * t;
            psv_r[t] = *reinterpret_cast<const uint4*>(&Ps[(size_t)src_l[r] * 128 + c8p]);
            pdv_r[t] = *reinterpret_cast<const uint4*>(&Pd[(size_t)dst_l[r] * 128 + c8p]);
        }
    }

    // ---- phase 3: fc3  W = H2 @ W3 -> Wts (regB) ----
    {
        f32x4 acc3[2][2];
#pragma unroll
        for (int n = 0; n < 2; ++n)
#pragma unroll
            for (int m = 0; m < 2; ++m) acc3[n][m] = (f32x4)(0.0f);
#pragma unroll
        for (int ks = 0; ks < 2; ++ks) {
            const int kk = lg * 8 + ks * 32;
            bf16x8 a[2];
#pragma unroll
            for (int m = 0; m < 2; ++m) {
                const int r = lr + 16 * m;
                const int byte = (r * 128 + kk * 2) ^ ((r & 7) << 4);
                a[m] = *reinterpret_cast<const bf16x8*>(regA + 4096 + byte);
            }
            bf16x8 b[2];
#pragma unroll
            for (int n = 0; n < 2; ++n) {
                const int c = 32 * w + 16 * n + lr;
                b[n] = *reinterpret_cast<const bf16x8*>(&Bt3[(size_t)c * 64 + kk]);
            }
#pragma unroll
            for (int n = 0; n < 2; ++n)
#pragma unroll
                for (int m = 0; m < 2; ++m) acc3[n][m] = MFMA16(a[m], b[n], acc3[n][m]);
        }
#pragma unroll
        for (int n = 0; n < 2; ++n) {
            const int c = 32 * w + 16 * n + lr;
#pragma unroll
            for (int m = 0; m < 2; ++m)
#pragma unroll
                for (int i = 0; i < 4; ++i) {
                    const int r = 16 * m + 4 * lg + i;
                    const int byte = (r * 256 + c * 2) ^ ((r & 7) << 4);
                    *reinterpret_cast<u16*>(regB + byte) = f2bf(acc3[n][m][i]);
                }
        }
    }
    __syncthreads();

    // ---- phase 4: epilogue IN PLACE on regB; Ps/Pd from prefetch regs ----
#pragma unroll
    for (int t = 0; t < 2; ++t) {
        const int idx = tid + 256 * t;
        const int r = idx >> 4;
        const int c8 = (idx & 15) * 8;
        if (e0 + r >= E) continue;
        const int byte = (r * 256 + c8 * 2) ^ ((r & 7) << 4);
        const uint4 wv = *reinterpret_cast<const uint4*>(regB + byte);
        const float wt[8] = {lo2f(wv.x), hi2f(wv.x), lo2f(wv.y), hi2f(wv.y),
                             lo2f(wv.z), hi2f(wv.z), lo2f(wv.w), hi2f(wv.w)};
        const float eav = ea_l[r];
        const uint4 psv = psv_r[t];
        const uint4 pdv = pdv_r[t];
        const float ps[8] = {lo2f(psv.x), hi2f(psv.x), lo2f(psv.y), hi2f(psv.y),
                             lo2f(psv.z), hi2f(psv.z), lo2f(psv.w), hi2f(psv.w)};
        const float pd[8] = {lo2f(pdv.x), hi2f(pdv.x), lo2f(pdv.y), hi2f(pdv.y),
                             lo2f(pdv.z), hi2f(pdv.z), lo2f(pdv.w), hi2f(pdv.w)};
        float m[8];
#pragma unroll
        for (int j = 0; j < 8; ++j) m[j] = (ps[j] + pd[j]) * eav * wt[j];
        u32 p0 = pack2(m[0], m[1]), p1 = pack2(m[2], m[3]);
        u32 p2 = pack2(m[4], m[5]), p3 = pack2(m[6], m[7]);
        *reinterpret_cast<uint4*>(regB + byte) = make_uint4(p0, p1, p2, p3);
    }
    __syncthreads();

    // ---- phase 5+6 fused, per-n: GEMM1 fragment -> immediate consume ----
    const int c0w = w * 64;
#pragma unroll
    for (int n = 0; n < 4; ++n) {
        f32x4 accn[2];
#pragma unroll
        for (int m = 0; m < 2; ++m) accn[m] = (f32x4)(0.0f);
#pragma unroll
        for (int ks = 0; ks < 4; ++ks) {
            const int kk = lg * 8 + ks * 32;
            const bf16x8 b = *reinterpret_cast<const bf16x8*>(
                &Wct[(size_t)(c0w + 16 * n + lr) * 128 + kk]);
#pragma unroll
            for (int m = 0; m < 2; ++m) {
                const int r = lr + 16 * m;
                const int byte = (r * 256 + kk * 2) ^ ((r & 7) << 4);
                const bf16x8 am = *reinterpret_cast<const bf16x8*>(regB + byte);
                accn[m] = MFMA16(am, b, accn[m]);
            }
        }
        if (w < 2) {
            const float ad = att_dot[c0w + 16 * n + lr];
            const int h = 4 * w + n;
#pragma unroll
            for (int m = 0; m < 2; ++m) {
#pragma unroll
                for (int i = 0; i < 4; ++i) {
                    float s = slreluf_(accn[m][i]) * ad;
                    s += __shfl_xor(s, 1);
                    s += __shfl_xor(s, 2);
                    s += __shfl_xor(s, 4);
                    s += __shfl_xor(s, 8);
                    if (lr == 0) lgs[(16 * m + 4 * lg + i) * 8 + h] = s;
                }
            }
        } else {
            const int cc = 64 * (w - 2) + 16 * n + lr;
            const float wi = w_int[cc];
#pragma unroll
            for (int m = 0; m < 2; ++m) {
#pragma unroll
                for (int i = 0; i < 4; ++i) {
                    const int r = 16 * m + 4 * lg + i;
                    const float v1 = siluf_(accn[m][i]) * ea_l[r] * wi;
                    const int byte = (r * 256 + cc * 2) ^ ((r & 7) << 4);
                    *reinterpret_cast<u16*>(regA + byte) = f2bf(v1);
                }
            }
        }
    }
    __syncthreads();  // V1 complete; all GEMM1 reads of regB done

    // ---- phase 7: GEMM2  V = V1 @ Wv; Vout -> regB ----
    {
        f32x4 acc2[2][2];
#pragma unroll
        for (int m = 0; m < 2; ++m)
#pragma unroll
            for (int n = 0; n < 2; ++n) acc2[m][n] = (f32x4)(0.0f);
#pragma unroll
        for (int ks = 0; ks < 4; ++ks) {
            const int kk = lg * 8 + ks * 32;
            bf16x8 a2[2], b2[2];
#pragma unroll
            for (int m = 0; m < 2; ++m) {
                const int r = lr + 16 * m;
                const int byte = (r * 256 + kk * 2) ^ ((r & 7) << 4);
                a2[m] = *reinterpret_cast<const bf16x8*>(regA + byte);
            }
#pragma unroll
            for (int n = 0; n < 2; ++n) {
                const int j = 32 * w + 16 * n + lr;
                b2[n] = *reinterpret_cast<const bf16x8*>(&Wvt[(size_t)j * 128 + kk]);
            }
#pragma unroll
            for (int m = 0; m < 2; ++m)
#pragma unroll
                for (int n = 0; n < 2; ++n) acc2[m][n] = MFMA16(a2[m], b2[n], acc2[m][n]);
        }
        u16* Vout = (u16*)regB;
#pragma unroll
        for (int n = 0; n < 2; ++n) {
            const int j = 32 * w + 16 * n + lr;
#pragma unroll
            for (int m = 0; m < 2; ++m)
#pragma unroll
                for (int i = 0; i < 4; ++i) {
                    const int r = 16 * m + 4 * lg + i;
                    Vout[r * 128 + j] = f2bf(acc2[m][n][i]);
                }
        }
    }
    __syncthreads();

    // ---- phase 8: fully sequential writeout (slot order) ----
    const uint4* vo = reinterpret_cast<const uint4*>(regB);
#pragma unroll
    for (int t = 0; t < 2; ++t) {
        const int idx = tid + 256 * t;  // 512 uint4 = 32 rows x 16
        const int row = idx >> 4;
        if (e0 + row < E)
            *reinterpret_cast<uint4*>(&V[(size_t)e0 * 128 + idx * 8]) = vo[idx];
    }
    if (tid < 64) {
        const int row = tid >> 1;  // 32 rows x 8 f32 = 64 float4
        if (e0 + row < E)
            *reinterpret_cast<float4*>(&LG[(size_t)e0 * 8 + tid * 4]) =
                *reinterpret_cast<const float4*>(&lgs[tid * 4]);
    }
}

// ---------------- CSR aggregation (wave-per-node), bf16 ACC out ----------------
__global__ __launch_bounds__(256) void aggregate_k(const int* __restrict__ rowptr,
                                                   const float* __restrict__ LG,
                                                   const u16* __restrict__ V,
                                                   u16* __restrict__ ACC, int Nn) {
    const int node = blockIdx.x * 4 + (threadIdx.x >> 6);
    const int lane = threadIdx.x & 63;
    if (node >= Nn) return;
    const int s = rowptr[node], t = rowptr[node + 1];
    const int h = lane >> 3;
    float a0 = 0.0f, a1 = 0.0f, ds = 0.0f;
    int i = s;
    for (; i + 3 < t; i += 4) {  // 4-deep unroll: 4 loads in flight
        float ex[4];
        u32 vv[4];
#pragma unroll
        for (int u = 0; u < 4; ++u) {
            ex[u] = __expf(LG[(size_t)(i + u) * 8 + h]);
            vv[u] = *reinterpret_cast<const u32*>(&V[(size_t)(i + u) * 128 + lane * 2]);
        }
#pragma unroll
        for (int u = 0; u < 4; ++u) {
            a0 += ex[u] * lo2f(vv[u]);
            a1 += ex[u] * hi2f(vv[u]);
            ds += ex[u];
        }
    }
    for (; i < t; ++i) {
        const float ex0 = __expf(LG[(size_t)i * 8 + h]);
        const u32 v0 = *reinterpret_cast<const u32*>(&V[(size_t)i * 128 + lane * 2]);
        a0 += ex0 * lo2f(v0);
        a1 += ex0 * hi2f(v0);
        ds += ex0;
    }
    const float inv = 1.0f / (ds + 1e-16f);
    *reinterpret_cast<u32*>(&ACC[(size_t)node * 128 + lane * 2]) = pack2(a0 * inv, a1 * inv);
}

// ---------------- output projection from bf16 ACC ----------------
__global__ __launch_bounds__(256) void outproj_mfma_k(const u16* __restrict__ A,
                                                      const u16* __restrict__ Wt,
                                                      const float* __restrict__ bias,
                                                      float* __restrict__ Out, int M) {
    const int tid  = threadIdx.x;
    const int lane = tid & 63;
    const int w    = tid >> 6;
    const int lr   = lane & 15;
    const int lg   = lane >> 4;
    const int e0   = blockIdx.x * 64;

    f32x4 acc[4][2];
#pragma unroll
    for (int m = 0; m < 4; ++m)
#pragma unroll
        for (int n = 0; n < 2; ++n) acc[m][n] = (f32x4)(0.0f);

#pragma unroll
    for (int ks = 0; ks < 4; ++ks) {
        const int kk = lg * 8 + ks * 32;
        bf16x8 a[4], b[2];
#pragma unroll
        for (int m = 0; m < 4; ++m) {
            int row = e0 + lr + 16 * m;
            row = (row < M) ? row : (M - 1);
            a[m] = *reinterpret_cast<const bf16x8*>(&A[(size_t)row * 128 + kk]);
        }
#pragma unroll
        for (int n = 0; n < 2; ++n) {
            const int c = 32 * w + 16 * n + lr;
            b[n] = *reinterpret_cast<const bf16x8*>(&Wt[(size_t)c * 128 + kk]);
        }
#pragma unroll
        for (int m = 0; m < 4; ++m)
#pragma unroll
            for (int n = 0; n < 2; ++n) acc[m][n] = MFMA16(a[m], b[n], acc[m][n]);
    }

#pragma unroll
    for (int n = 0; n < 2; ++n) {
        const int j = 32 * w + 16 * n + lr;
        const float bv = bias[j];
#pragma unroll
        for (int m = 0; m < 4; ++m)
#pragma unroll
            for (int i = 0; i < 4; ++i) {
                const int row = e0 + 16 * m + 4 * lg + i;
                if (row < M) Out[(size_t)row * 128 + j] = acc[m][n][i] + bv;
            }
    }
}

// ---------------- launch ----------------
extern "C" void kernel_launch(void* const* d_in, const int* in_sizes, int n_in,
                              void* d_out, int out_size, void* d_ws, size_t ws_size,
                              hipStream_t stream) {
    const float* node_feats = (const float*)d_in[0];
    const float* node_attr  = (const float*)d_in[1];
    const float* edge_attr  = (const float*)d_in[2];
    const float* edge_emb   = (const float*)d_in[3];
    const float* W_src      = (const float*)d_in[4];
    const float* b_src      = (const float*)d_in[5];
    const float* W_dst      = (const float*)d_in[6];
    const float* W_fc1      = (const float*)d_in[7];
    const float* b_fc1      = (const float*)d_in[8];
    const float* W_fc2      = (const float*)d_in[9];
    const float* b_fc2      = (const float*)d_in[10];
    const float* W_fc3      = (const float*)d_in[11];
    const float* W_alpha    = (const float*)d_in[12];
    const float* W_lin      = (const float*)d_in[13];
    const float* w_int      = (const float*)d_in[14];
    const float* W_val      = (const float*)d_in[15];
    const float* att_dot    = (const float*)d_in[16];
    const float* W_out      = (const float*)d_in[17];
    const float* b_out      = (const float*)d_in[18];
    const int* esrc         = (const int*)d_in[19];
    const int* edst         = (const int*)d_in[20];

    const int Nn = in_sizes[0] / 128;  // 30000
    const int E  = in_sizes[19];       // 480000

    char* w = (char*)d_ws;
    auto alloc = [&](size_t bytes) {
        char* p = w;
        w += (bytes + 255) & ~(size_t)255;
        return p;
    };
    u16* V      = (u16*)alloc((size_t)E * 128 * 2);    // CSR-ordered
    float* LG   = (float*)alloc((size_t)E * 8 * 4);    // CSR-ordered
    u16* Psrc   = (u16*)alloc((size_t)Nn * 128 * 2);   // bf16
    u16* Pdst   = (u16*)alloc((size_t)Nn * 128 * 2);   // bf16
    u16* ACC    = (u16*)alloc((size_t)Nn * 128 * 2);   // bf16
    int* deg    = (int*)alloc((size_t)Nn * 4);
    int* rowptr = (int*)alloc((size_t)(Nn + 1) * 4);
    int* cursor = (int*)alloc((size_t)Nn * 4);
    int* eids   = (int*)alloc((size_t)E * 4);
    u16* Wct    = (u16*)alloc(32768 * 2);
    u16* Wvt    = (u16*)alloc(16384 * 2);
    u16* Bt1    = (u16*)alloc(4096 * 2);
    u16* Bt2    = (u16*)alloc(4096 * 2);
    u16* Bt3    = (u16*)alloc(8192 * 2);
    u16* Wst    = (u16*)alloc(16384 * 2);
    u16* Wdt    = (u16*)alloc(16384 * 2);
    u16* Wot    = (u16*)alloc(16384 * 2);

    // CSR build + weight prep
    hipMemsetAsync(deg, 0, (size_t)Nn * 4, stream);
    hist_k<<<(E + 255) / 256, 256, 0, stream>>>(edst, deg, E);
    scan_k<<<1, 1024, 0, stream>>>(deg, rowptr, cursor, Nn);
    fill_k<<<(E + 255) / 256, 256, 0, stream>>>(edst, cursor, eids, E);
    prep_w_k<<<448, 256, 0, stream>>>(W_alpha, W_lin, W_val, W_fc1, W_fc2, W_fc3,
                                      W_src, W_dst, W_out,
                                      Wct, Wvt, Bt1, Bt2, Bt3, Wst, Wdt, Wot);

    const int nb_node = (Nn + 63) / 64;  // 469
    const int nb_e    = (E + 31) / 32;   // 15000

    proj2_mfma_k<<<nb_node, 256, 0, stream>>>(node_feats, Wst, Wdt, b_src, Psrc, Pdst, Nn);

    msg_attn_k<<<nb_e, 256, 0, stream>>>(edge_emb, node_attr, edge_attr, esrc, edst, eids,
                                         Bt1, b_fc1, Bt2, b_fc2, Bt3,
                                         Psrc, Pdst, Wct, Wvt, att_dot, w_int,
                                         LG, V, E);

    aggregate_k<<<(Nn + 3) / 4, 256, 0, stream>>>(rowptr, LG, V, ACC, Nn);

    outproj_mfma_k<<<nb_node, 256, 0, stream>>>(ACC, Wot, b_out, (float*)d_out, Nn);
}

// Round 19
// 477.193 us; speedup vs baseline: 1.1127x; 1.1127x over previous
//
#include <hip/hip_runtime.h>
#include <hip/hip_bf16.h>
#include <cstdint>
#include <cstddef>

// GraphAttentionLayer: N=30000, E=480000, C=128, H=8, DH=16, NB=32, NA=16, FC=64.
//
// R19 vs R18 (TILE-32 at bound 8: occupancy hit 89% BUT allocator capped at
// 64 VGPR -> spilled everything; VGPR_Count 32, WRITE 465MB, 401us):
//   __launch_bounds__(256, 6): VGPR cap 85 (> ~60 needed -> no spill);
//   LDS 17920 x 6 = 107.5KB -> 6 blocks/CU = 75% occupancy (vs R16's 44%).
//   Single-token diff from R18 isolates occupancy-gain vs spill-cost.
//   Diagnostic: WRITE ~165MB + VGPR ~60 = clean; dur >=300 -> revert R16.

typedef unsigned short u16;
typedef unsigned int u32;
typedef __attribute__((ext_vector_type(8))) short bf16x8;
typedef __attribute__((ext_vector_type(4))) float f32x4;

union fu_ { float f; u32 u; };
static __device__ __forceinline__ float lo2f(u32 v) { fu_ x; x.u = v << 16; return x.f; }
static __device__ __forceinline__ float hi2f(u32 v) { fu_ x; x.u = v & 0xFFFF0000u; return x.f; }
static __device__ __forceinline__ u16 f2bf(float f) {
    union { __hip_bfloat16 h; u16 u; } c;
    c.h = __float2bfloat16(f);
    return c.u;
}
static __device__ __forceinline__ u32 pack2(float a, float b) {
    return (u32)f2bf(a) | ((u32)f2bf(b) << 16);
}
static __device__ __forceinline__ float sigmoidf_(float x) { return 1.0f / (1.0f + __expf(-x)); }
static __device__ __forceinline__ float siluf_(float x)    { return x * sigmoidf_(x); }
static __device__ __forceinline__ float slreluf_(float x)  { return x * (0.2f + 0.8f * sigmoidf_(x)); }

#define MFMA16(a, b, c) __builtin_amdgcn_mfma_f32_16x16x32_bf16((a), (b), (c), 0, 0, 0)

static __device__ __forceinline__ bf16x8 ld8f_bf(const float* __restrict__ p) {
    const float4 x = *reinterpret_cast<const float4*>(p);
    const float4 y = *reinterpret_cast<const float4*>(p + 4);
    bf16x8 r;
    r[0] = (short)f2bf(x.x); r[1] = (short)f2bf(x.y);
    r[2] = (short)f2bf(x.z); r[3] = (short)f2bf(x.w);
    r[4] = (short)f2bf(y.x); r[5] = (short)f2bf(y.y);
    r[6] = (short)f2bf(y.z); r[7] = (short)f2bf(y.w);
    return r;
}

// bijective XCD swizzle (m204)
static __device__ __forceinline__ int xcd_swz(int orig, int nwg) {
    const int q = nwg >> 3, rr = nwg & 7;
    const int xcd = orig & 7, idx = orig >> 3;
    return (xcd < rr ? xcd * (q + 1) : rr * (q + 1) + (xcd - rr) * q) + idx;
}

// ---------------- CSR build ----------------
__global__ void hist_k(const int* __restrict__ dst, int* __restrict__ deg, int E) {
    int i = blockIdx.x * blockDim.x + threadIdx.x;
    if (i < E) atomicAdd(&deg[dst[i]], 1);
}

__global__ void scan_k(const int* __restrict__ deg, int* __restrict__ rowptr,
                       int* __restrict__ cursor, int n) {
    __shared__ int part[1024];
    const int t = threadIdx.x;
    const int C = (n + 1023) / 1024;
    const int lo = t * C;
    const int hi = (lo + C < n) ? (lo + C) : n;
    int s = 0;
    for (int i = lo; i < hi; ++i) s += deg[i];
    part[t] = s;
    __syncthreads();
    for (int off = 1; off < 1024; off <<= 1) {
        int v = part[t];
        int u = (t >= off) ? part[t - off] : 0;
        __syncthreads();
        part[t] = v + u;
        __syncthreads();
    }
    int excl = (t == 0) ? 0 : part[t - 1];
    for (int i = lo; i < hi; ++i) {
        rowptr[i] = excl;
        cursor[i] = excl;
        excl += deg[i];
    }
    if (t == 1023) rowptr[n] = part[1023];
}

__global__ void fill_k(const int* __restrict__ dst, int* __restrict__ cursor,
                       int* __restrict__ eids, int E) {
    int i = blockIdx.x * blockDim.x + threadIdx.x;
    if (i < E) {
        int d = dst[i];
        int p = atomicAdd(&cursor[d], 1);
        eids[p] = i;
    }
}

// ---------------- weight prep (all transposed, bf16) ----------------
__global__ void prep_w_k(const float* __restrict__ Wa, const float* __restrict__ Wl,
                         const float* __restrict__ Wv,
                         const float* __restrict__ W1, const float* __restrict__ W2,
                         const float* __restrict__ W3,
                         const float* __restrict__ Wsrc, const float* __restrict__ Wdst,
                         const float* __restrict__ Wout,
                         u16* __restrict__ Wct, u16* __restrict__ Wvt,
                         u16* __restrict__ Bt1, u16* __restrict__ Bt2,
                         u16* __restrict__ Bt3,
                         u16* __restrict__ Wst, u16* __restrict__ Wdt,
                         u16* __restrict__ Wot) {
    int idx = blockIdx.x * 256 + threadIdx.x;
    if (idx < 32768) {
        int c = idx >> 7, k = idx & 127;
        float v = (c < 128) ? Wa[(size_t)k * 128 + c] : Wl[(size_t)k * 128 + (c - 128)];
        Wct[idx] = f2bf(v);
    } else if (idx < 49152) {
        int t = idx - 32768;
        int j = t >> 7, c = t & 127;
        Wvt[t] = f2bf(Wv[(size_t)c * 128 + j]);
    } else if (idx < 53248) {
        int t = idx - 49152;
        int c = t >> 6, k = t & 63;
        Bt1[t] = f2bf(W1[(size_t)k * 64 + c]);
    } else if (idx < 57344) {
        int t = idx - 53248;
        int c = t >> 6, k = t & 63;
        Bt2[t] = f2bf(W2[(size_t)k * 64 + c]);
    } else if (idx < 65536) {
        int t = idx - 57344;
        int c = t >> 6, k = t & 63;
        Bt3[t] = f2bf(W3[(size_t)k * 128 + c]);
    } else if (idx < 81920) {
        int t = idx - 65536;
        int c = t >> 7, k = t & 127;
        Wst[t] = f2bf(Wsrc[(size_t)k * 128 + c]);
    } else if (idx < 98304) {
        int t = idx - 81920;
        int c = t >> 7, k = t & 127;
        Wdt[t] = f2bf(Wdst[(size_t)k * 128 + c]);
    } else if (idx < 114688) {
        int t = idx - 98304;
        int c = t >> 7, k = t & 127;
        Wot[t] = f2bf(Wout[(size_t)k * 128 + c]);
    }
}

// ---------------- dual node projection: Psrc,Pdst (bf16 out) in one pass ----------------
__global__ __launch_bounds__(256) void proj2_mfma_k(const float* __restrict__ A,
                                                    const u16* __restrict__ Wt1,
                                                    const u16* __restrict__ Wt2,
                                                    const float* __restrict__ bias1,
                                                    u16* __restrict__ O1,
                                                    u16* __restrict__ O2, int M) {
    const int tid  = threadIdx.x;
    const int lane = tid & 63;
    const int w    = tid >> 6;
    const int lr   = lane & 15;
    const int lg   = lane >> 4;
    const int e0   = blockIdx.x * 64;

    f32x4 acc1[4][2], acc2[4][2];
#pragma unroll
    for (int m = 0; m < 4; ++m)
#pragma unroll
        for (int n = 0; n < 2; ++n) { acc1[m][n] = (f32x4)(0.0f); acc2[m][n] = (f32x4)(0.0f); }

#pragma unroll
    for (int ks = 0; ks < 4; ++ks) {
        const int kk = lg * 8 + ks * 32;
        bf16x8 a[4], b1v[2], b2v[2];
#pragma unroll
        for (int m = 0; m < 4; ++m) {
            int row = e0 + lr + 16 * m;
            row = (row < M) ? row : (M - 1);
            a[m] = ld8f_bf(&A[(size_t)row * 128 + kk]);
        }
#pragma unroll
        for (int n = 0; n < 2; ++n) {
            const int c = 32 * w + 16 * n + lr;
            b1v[n] = *reinterpret_cast<const bf16x8*>(&Wt1[(size_t)c * 128 + kk]);
            b2v[n] = *reinterpret_cast<const bf16x8*>(&Wt2[(size_t)c * 128 + kk]);
        }
#pragma unroll
        for (int m = 0; m < 4; ++m)
#pragma unroll
            for (int n = 0; n < 2; ++n) {
                acc1[m][n] = MFMA16(a[m], b1v[n], acc1[m][n]);
                acc2[m][n] = MFMA16(a[m], b2v[n], acc2[m][n]);
            }
    }

#pragma unroll
    for (int n = 0; n < 2; ++n) {
        const int j = 32 * w + 16 * n + lr;
        const float bv = bias1[j];
#pragma unroll
        for (int m = 0; m < 4; ++m)
#pragma unroll
            for (int i = 0; i < 4; ++i) {
                const int row = e0 + 16 * m + 4 * lg + i;
                if (row < M) {
                    O1[(size_t)row * 128 + j] = f2bf(acc1[m][n][i] + bv);
                    O2[(size_t)row * 128 + j] = f2bf(acc2[m][n][i]);
                }
            }
    }
}

// ---------------- fused radial MLP + message + attention + value ----------------
// TILE=32 edges; LDS 17920 B; bound(256,6) -> 6 blocks/CU, VGPR cap 85 (no spill).
__global__ __launch_bounds__(256, 6) void msg_attn_k(
    const float* __restrict__ eemb, const float* __restrict__ nattr,
    const float* __restrict__ ea,
    const int* __restrict__ src, const int* __restrict__ dst,
    const int* __restrict__ eids,
    const u16* __restrict__ Bt1, const float* __restrict__ b1,
    const u16* __restrict__ Bt2, const float* __restrict__ b2,
    const u16* __restrict__ Bt3,
    const u16* __restrict__ Ps, const u16* __restrict__ Pd,
    const u16* __restrict__ Wct, const u16* __restrict__ Wvt,
    const float* __restrict__ att_dot, const float* __restrict__ w_int,
    float* __restrict__ LG, u16* __restrict__ V, int E) {
    __shared__ __align__(16) char smem[17920];
    char* regA   = smem;                    // H1 [0,4K) + H2 [4K,8K); later V1s (8K)
    char* regB   = smem + 8192;             // Wts -> MSG (in place) -> Vout (8K)
    float* lgs   = (float*)(smem + 16384);  // 32*8 f32 = 1K
    int*   eid_l = (int*)(smem + 17408);    // [32]
    int*   src_l = eid_l + 32;
    int*   dst_l = src_l + 32;
    float* ea_l  = (float*)(dst_l + 32);    // [32]

    const int tid  = threadIdx.x;
    const int lane = tid & 63;
    const int w    = tid >> 6;
    const int lr   = lane & 15;
    const int lg   = lane >> 4;
    const int e0   = xcd_swz(blockIdx.x, gridDim.x) * 32;  // CSR slot base

    // ---- phase 0: stage slot->edge metadata ----
    if (tid < 32) {
        int slot = e0 + tid;
        int e = (slot < E) ? eids[slot] : eids[E - 1];
        eid_l[tid] = e;
        src_l[tid] = src[e];
        dst_l[tid] = dst[e];
        ea_l[tid]  = ea[e];
    }
    __syncthreads();

    // ---- phase 1: fc1  H1 = silu(WF @ W1 + b1), A gathered via eid ----
    {
        f32x4 acc1[2];
#pragma unroll
        for (int m = 0; m < 2; ++m) acc1[m] = (f32x4)(0.0f);
#pragma unroll
        for (int ks = 0; ks < 2; ++ks) {
            const int kk = lg * 8 + ks * 32;
            bf16x8 a[2];
#pragma unroll
            for (int m = 0; m < 2; ++m) {
                const int r = lr + 16 * m;
                const float* ap;
                if (kk < 32)      ap = &eemb[(size_t)eid_l[r] * 32 + kk];
                else if (kk < 48) ap = &nattr[(size_t)src_l[r] * 16 + (kk - 32)];
                else              ap = &nattr[(size_t)dst_l[r] * 16 + (kk - 48)];
                a[m] = ld8f_bf(ap);
            }
            const bf16x8 b = *reinterpret_cast<const bf16x8*>(&Bt1[(size_t)(16 * w + lr) * 64 + kk]);
#pragma unroll
            for (int m = 0; m < 2; ++m) acc1[m] = MFMA16(a[m], b, acc1[m]);
        }
        const int c = 16 * w + lr;
        const float bias = b1[c];
#pragma unroll
        for (int m = 0; m < 2; ++m)
#pragma unroll
            for (int i = 0; i < 4; ++i) {
                const int r = 16 * m + 4 * lg + i;
                const int byte = (r * 128 + c * 2) ^ ((r & 7) << 4);
                *reinterpret_cast<u16*>(regA + byte) = f2bf(siluf_(acc1[m][i] + bias));
            }
    }
    __syncthreads();

    // ---- phase 2: fc2  H2 = silu(H1 @ W2 + b2) ----
    {
        f32x4 acc2[2];
#pragma unroll
        for (int m = 0; m < 2; ++m) acc2[m] = (f32x4)(0.0f);
#pragma unroll
        for (int ks = 0; ks < 2; ++ks) {
            const int kk = lg * 8 + ks * 32;
            bf16x8 a[2];
#pragma unroll
            for (int m = 0; m < 2; ++m) {
                const int r = lr + 16 * m;
                const int byte = (r * 128 + kk * 2) ^ ((r & 7) << 4);
                a[m] = *reinterpret_cast<const bf16x8*>(regA + byte);
            }
            const bf16x8 b = *reinterpret_cast<const bf16x8*>(&Bt2[(size_t)(16 * w + lr) * 64 + kk]);
#pragma unroll
            for (int m = 0; m < 2; ++m) acc2[m] = MFMA16(a[m], b, acc2[m]);
        }
        const int c = 16 * w + lr;
        const float bias = b2[c];
#pragma unroll
        for (int m = 0; m < 2; ++m)
#pragma unroll
            for (int i = 0; i < 4; ++i) {
                const int r = 16 * m + 4 * lg + i;
                const int byte = (r * 128 + c * 2) ^ ((r & 7) << 4);
                *reinterpret_cast<u16*>(regA + 4096 + byte) = f2bf(siluf_(acc2[m][i] + bias));
            }
    }
    __syncthreads();

    // ---- prefetch (short range): epilogue Ps/Pd, consumed in phase 4 ----
    uint4 psv_r[2], pdv_r[2];
    {
        const int c8p = (tid & 15) * 8;
#pragma unroll
        for (int t = 0; t < 2; ++t) {
            const int r = (tid >> 4) + 16 * t;
            psv_r[t] = *reinterpret_cast<const uint4*>(&Ps[(size_t)src_l[r] * 128 + c8p]);
            pdv_r[t] = *reinterpret_cast<const uint4*>(&Pd[(size_t)dst_l[r] * 128 + c8p]);
        }
    }

    // ---- phase 3: fc3  W = H2 @ W3 -> Wts (regB) ----
    {
        f32x4 acc3[2][2];
#pragma unroll
        for (int n = 0; n < 2; ++n)
#pragma unroll
            for (int m = 0; m < 2; ++m) acc3[n][m] = (f32x4)(0.0f);
#pragma unroll
        for (int ks = 0; ks < 2; ++ks) {
            const int kk = lg * 8 + ks * 32;
            bf16x8 a[2];
#pragma unroll
            for (int m = 0; m < 2; ++m) {
                const int r = lr + 16 * m;
                const int byte = (r * 128 + kk * 2) ^ ((r & 7) << 4);
                a[m] = *reinterpret_cast<const bf16x8*>(regA + 4096 + byte);
            }
            bf16x8 b[2];
#pragma unroll
            for (int n = 0; n < 2; ++n) {
                const int c = 32 * w + 16 * n + lr;
                b[n] = *reinterpret_cast<const bf16x8*>(&Bt3[(size_t)c * 64 + kk]);
            }
#pragma unroll
            for (int n = 0; n < 2; ++n)
#pragma unroll
                for (int m = 0; m < 2; ++m) acc3[n][m] = MFMA16(a[m], b[n], acc3[n][m]);
        }
#pragma unroll
        for (int n = 0; n < 2; ++n) {
            const int c = 32 * w + 16 * n + lr;
#pragma unroll
            for (int m = 0; m < 2; ++m)
#pragma unroll
                for (int i = 0; i < 4; ++i) {
                    const int r = 16 * m + 4 * lg + i;
                    const int byte = (r * 256 + c * 2) ^ ((r & 7) << 4);
                    *reinterpret_cast<u16*>(regB + byte) = f2bf(acc3[n][m][i]);
                }
        }
    }
    __syncthreads();

    // ---- phase 4: epilogue IN PLACE on regB; Ps/Pd from prefetch regs ----
#pragma unroll
    for (int t = 0; t < 2; ++t) {
        const int idx = tid + 256 * t;
        const int r = idx >> 4;
        const int c8 = (idx & 15) * 8;
        if (e0 + r >= E) continue;
        const int byte = (r * 256 + c8 * 2) ^ ((r & 7) << 4);
        const uint4 wv = *reinterpret_cast<const uint4*>(regB + byte);
        const float wt[8] = {lo2f(wv.x), hi2f(wv.x), lo2f(wv.y), hi2f(wv.y),
                             lo2f(wv.z), hi2f(wv.z), lo2f(wv.w), hi2f(wv.w)};
        const float eav = ea_l[r];
        const uint4 psv = psv_r[t];
        const uint4 pdv = pdv_r[t];
        const float ps[8] = {lo2f(psv.x), hi2f(psv.x), lo2f(psv.y), hi2f(psv.y),
                             lo2f(psv.z), hi2f(psv.z), lo2f(psv.w), hi2f(psv.w)};
        const float pd[8] = {lo2f(pdv.x), hi2f(pdv.x), lo2f(pdv.y), hi2f(pdv.y),
                             lo2f(pdv.z), hi2f(pdv.z), lo2f(pdv.w), hi2f(pdv.w)};
        float m[8];
#pragma unroll
        for (int j = 0; j < 8; ++j) m[j] = (ps[j] + pd[j]) * eav * wt[j];
        u32 p0 = pack2(m[0], m[1]), p1 = pack2(m[2], m[3]);
        u32 p2 = pack2(m[4], m[5]), p3 = pack2(m[6], m[7]);
        *reinterpret_cast<uint4*>(regB + byte) = make_uint4(p0, p1, p2, p3);
    }
    __syncthreads();

    // ---- phase 5+6 fused, per-n: GEMM1 fragment -> immediate consume ----
    const int c0w = w * 64;
#pragma unroll
    for (int n = 0; n < 4; ++n) {
        f32x4 accn[2];
#pragma unroll
        for (int m = 0; m < 2; ++m) accn[m] = (f32x4)(0.0f);
#pragma unroll
        for (int ks = 0; ks < 4; ++ks) {
            const int kk = lg * 8 + ks * 32;
            const bf16x8 b = *reinterpret_cast<const bf16x8*>(
                &Wct[(size_t)(c0w + 16 * n + lr) * 128 + kk]);
#pragma unroll
            for (int m = 0; m < 2; ++m) {
                const int r = lr + 16 * m;
                const int byte = (r * 256 + kk * 2) ^ ((r & 7) << 4);
                const bf16x8 am = *reinterpret_cast<const bf16x8*>(regB + byte);
                accn[m] = MFMA16(am, b, accn[m]);
            }
        }
        if (w < 2) {
            const float ad = att_dot[c0w + 16 * n + lr];
            const int h = 4 * w + n;
#pragma unroll
            for (int m = 0; m < 2; ++m) {
#pragma unroll
                for (int i = 0; i < 4; ++i) {
                    float s = slreluf_(accn[m][i]) * ad;
                    s += __shfl_xor(s, 1);
                    s += __shfl_xor(s, 2);
                    s += __shfl_xor(s, 4);
                    s += __shfl_xor(s, 8);
                    if (lr == 0) lgs[(16 * m + 4 * lg + i) * 8 + h] = s;
                }
            }
        } else {
            const int cc = 64 * (w - 2) + 16 * n + lr;
            const float wi = w_int[cc];
#pragma unroll
            for (int m = 0; m < 2; ++m) {
#pragma unroll
                for (int i = 0; i < 4; ++i) {
                    const int r = 16 * m + 4 * lg + i;
                    const float v1 = siluf_(accn[m][i]) * ea_l[r] * wi;
                    const int byte = (r * 256 + cc * 2) ^ ((r & 7) << 4);
                    *reinterpret_cast<u16*>(regA + byte) = f2bf(v1);
                }
            }
        }
    }
    __syncthreads();  // V1 complete; all GEMM1 reads of regB done

    // ---- phase 7: GEMM2  V = V1 @ Wv; Vout -> regB ----
    {
        f32x4 acc2[2][2];
#pragma unroll
        for (int m = 0; m < 2; ++m)
#pragma unroll
            for (int n = 0; n < 2; ++n) acc2[m][n] = (f32x4)(0.0f);
#pragma unroll
        for (int ks = 0; ks < 4; ++ks) {
            const int kk = lg * 8 + ks * 32;
            bf16x8 a2[2], b2[2];
#pragma unroll
            for (int m = 0; m < 2; ++m) {
                const int r = lr + 16 * m;
                const int byte = (r * 256 + kk * 2) ^ ((r & 7) << 4);
                a2[m] = *reinterpret_cast<const bf16x8*>(regA + byte);
            }
#pragma unroll
            for (int n = 0; n < 2; ++n) {
                const int j = 32 * w + 16 * n + lr;
                b2[n] = *reinterpret_cast<const bf16x8*>(&Wvt[(size_t)j * 128 + kk]);
            }
#pragma unroll
            for (int m = 0; m < 2; ++m)
#pragma unroll
                for (int n = 0; n < 2; ++n) acc2[m][n] = MFMA16(a2[m], b2[n], acc2[m][n]);
        }
        u16* Vout = (u16*)regB;
#pragma unroll
        for (int n = 0; n < 2; ++n) {
            const int j = 32 * w + 16 * n + lr;
#pragma unroll
            for (int m = 0; m < 2; ++m)
#pragma unroll
                for (int i = 0; i < 4; ++i) {
                    const int r = 16 * m + 4 * lg + i;
                    Vout[r * 128 + j] = f2bf(acc2[m][n][i]);
                }
        }
    }
    __syncthreads();

    // ---- phase 8: fully sequential writeout (slot order) ----
    const uint4* vo = reinterpret_cast<const uint4*>(regB);
#pragma unroll
    for (int t = 0; t < 2; ++t) {
        const int idx = tid + 256 * t;  // 512 uint4 = 32 rows x 16
        const int row = idx >> 4;
        if (e0 + row < E)
            *reinterpret_cast<uint4*>(&V[(size_t)e0 * 128 + idx * 8]) = vo[idx];
    }
    if (tid < 64) {
        const int row = tid >> 1;  // 32 rows x 8 f32 = 64 float4
        if (e0 + row < E)
            *reinterpret_cast<float4*>(&LG[(size_t)e0 * 8 + tid * 4]) =
                *reinterpret_cast<const float4*>(&lgs[tid * 4]);
    }
}

// ---------------- CSR aggregation (wave-per-node), bf16 ACC out ----------------
__global__ __launch_bounds__(256) void aggregate_k(const int* __restrict__ rowptr,
                                                   const float* __restrict__ LG,
                                                   const u16* __restrict__ V,
                                                   u16* __restrict__ ACC, int Nn) {
    const int node = blockIdx.x * 4 + (threadIdx.x >> 6);
    const int lane = threadIdx.x & 63;
    if (node >= Nn) return;
    const int s = rowptr[node], t = rowptr[node + 1];
    const int h = lane >> 3;
    float a0 = 0.0f, a1 = 0.0f, ds = 0.0f;
    int i = s;
    for (; i + 3 < t; i += 4) {  // 4-deep unroll: 4 loads in flight
        float ex[4];
        u32 vv[4];
#pragma unroll
        for (int u = 0; u < 4; ++u) {
            ex[u] = __expf(LG[(size_t)(i + u) * 8 + h]);
            vv[u] = *reinterpret_cast<const u32*>(&V[(size_t)(i + u) * 128 + lane * 2]);
        }
#pragma unroll
        for (int u = 0; u < 4; ++u) {
            a0 += ex[u] * lo2f(vv[u]);
            a1 += ex[u] * hi2f(vv[u]);
            ds += ex[u];
        }
    }
    for (; i < t; ++i) {
        const float ex0 = __expf(LG[(size_t)i * 8 + h]);
        const u32 v0 = *reinterpret_cast<const u32*>(&V[(size_t)i * 128 + lane * 2]);
        a0 += ex0 * lo2f(v0);
        a1 += ex0 * hi2f(v0);
        ds += ex0;
    }
    const float inv = 1.0f / (ds + 1e-16f);
    *reinterpret_cast<u32*>(&ACC[(size_t)node * 128 + lane * 2]) = pack2(a0 * inv, a1 * inv);
}

// ---------------- output projection from bf16 ACC ----------------
__global__ __launch_bounds__(256) void outproj_mfma_k(const u16* __restrict__ A,
                                                      const u16* __restrict__ Wt,
                                                      const float* __restrict__ bias,
                                                      float* __restrict__ Out, int M) {
    const int tid  = threadIdx.x;
    const int lane = tid & 63;
    const int w    = tid >> 6;
    const int lr   = lane & 15;
    const int lg   = lane >> 4;
    const int e0   = blockIdx.x * 64;

    f32x4 acc[4][2];
#pragma unroll
    for (int m = 0; m < 4; ++m)
#pragma unroll
        for (int n = 0; n < 2; ++n) acc[m][n] = (f32x4)(0.0f);

#pragma unroll
    for (int ks = 0; ks < 4; ++ks) {
        const int kk = lg * 8 + ks * 32;
        bf16x8 a[4], b[2];
#pragma unroll
        for (int m = 0; m < 4; ++m) {
            int row = e0 + lr + 16 * m;
            row = (row < M) ? row : (M - 1);
            a[m] = *reinterpret_cast<const bf16x8*>(&A[(size_t)row * 128 + kk]);
        }
#pragma unroll
        for (int n = 0; n < 2; ++n) {
            const int c = 32 * w + 16 * n + lr;
            b[n] = *reinterpret_cast<const bf16x8*>(&Wt[(size_t)c * 128 + kk]);
        }
#pragma unroll
        for (int m = 0; m < 4; ++m)
#pragma unroll
            for (int n = 0; n < 2; ++n) acc[m][n] = MFMA16(a[m], b[n], acc[m][n]);
    }

#pragma unroll
    for (int n = 0; n < 2; ++n) {
        const int j = 32 * w + 16 * n + lr;
        const float bv = bias[j];
#pragma unroll
        for (int m = 0; m < 4; ++m)
#pragma unroll
            for (int i = 0; i < 4; ++i) {
                const int row = e0 + 16 * m + 4 * lg + i;
                if (row < M) Out[(size_t)row * 128 + j] = acc[m][n][i] + bv;
            }
    }
}

// ---------------- launch ----------------
extern "C" void kernel_launch(void* const* d_in, const int* in_sizes, int n_in,
                              void* d_out, int out_size, void* d_ws, size_t ws_size,
                              hipStream_t stream) {
    const float* node_feats = (const float*)d_in[0];
    const float* node_attr  = (const float*)d_in[1];
    const float* edge_attr  = (const float*)d_in[2];
    const float* edge_emb   = (const float*)d_in[3];
    const float* W_src      = (const float*)d_in[4];
    const float* b_src      = (const float*)d_in[5];
    const float* W_dst      = (const float*)d_in[6];
    const float* W_fc1      = (const float*)d_in[7];
    const float* b_fc1      = (const float*)d_in[8];
    const float* W_fc2      = (const float*)d_in[9];
    const float* b_fc2      = (const float*)d_in[10];
    const float* W_fc3      = (const float*)d_in[11];
    const float* W_alpha    = (const float*)d_in[12];
    const float* W_lin      = (const float*)d_in[13];
    const float* w_int      = (const float*)d_in[14];
    const float* W_val      = (const float*)d_in[15];
    const float* att_dot    = (const float*)d_in[16];
    const float* W_out      = (const float*)d_in[17];
    const float* b_out      = (const float*)d_in[18];
    const int* esrc         = (const int*)d_in[19];
    const int* edst         = (const int*)d_in[20];

    const int Nn = in_sizes[0] / 128;  // 30000
    const int E  = in_sizes[19];       // 480000

    char* w = (char*)d_ws;
    auto alloc = [&](size_t bytes) {
        char* p = w;
        w += (bytes + 255) & ~(size_t)255;
        return p;
    };
    u16* V      = (u16*)alloc((size_t)E * 128 * 2);    // CSR-ordered
    float* LG   = (float*)alloc((size_t)E * 8 * 4);    // CSR-ordered
    u16* Psrc   = (u16*)alloc((size_t)Nn * 128 * 2);   // bf16
    u16* Pdst   = (u16*)alloc((size_t)Nn * 128 * 2);   // bf16
    u16* ACC    = (u16*)alloc((size_t)Nn * 128 * 2);   // bf16
    int* deg    = (int*)alloc((size_t)Nn * 4);
    int* rowptr = (int*)alloc((size_t)(Nn + 1) * 4);
    int* cursor = (int*)alloc((size_t)Nn * 4);
    int* eids   = (int*)alloc((size_t)E * 4);
    u16* Wct    = (u16*)alloc(32768 * 2);
    u16* Wvt    = (u16*)alloc(16384 * 2);
    u16* Bt1    = (u16*)alloc(4096 * 2);
    u16* Bt2    = (u16*)alloc(4096 * 2);
    u16* Bt3    = (u16*)alloc(8192 * 2);
    u16* Wst    = (u16*)alloc(16384 * 2);
    u16* Wdt    = (u16*)alloc(16384 * 2);
    u16* Wot    = (u16*)alloc(16384 * 2);

    // CSR build + weight prep
    hipMemsetAsync(deg, 0, (size_t)Nn * 4, stream);
    hist_k<<<(E + 255) / 256, 256, 0, stream>>>(edst, deg, E);
    scan_k<<<1, 1024, 0, stream>>>(deg, rowptr, cursor, Nn);
    fill_k<<<(E + 255) / 256, 256, 0, stream>>>(edst, cursor, eids, E);
    prep_w_k<<<448, 256, 0, stream>>>(W_alpha, W_lin, W_val, W_fc1, W_fc2, W_fc3,
                                      W_src, W_dst, W_out,
                                      Wct, Wvt, Bt1, Bt2, Bt3, Wst, Wdt, Wot);

    const int nb_node = (Nn + 63) / 64;  // 469
    const int nb_e    = (E + 31) / 32;   // 15000

    proj2_mfma_k<<<nb_node, 256, 0, stream>>>(node_feats, Wst, Wdt, b_src, Psrc, Pdst, Nn);

    msg_attn_k<<<nb_e, 256, 0, stream>>>(edge_emb, node_attr, edge_attr, esrc, edst, eids,
                                         Bt1, b_fc1, Bt2, b_fc2, Bt3,
                                         Psrc, Pdst, Wct, Wvt, att_dot, w_int,
                                         LG, V, E);

    aggregate_k<<<(Nn + 3) / 4, 256, 0, stream>>>(rowptr, LG, V, ACC, Nn);

    outproj_mfma_k<<<nb_node, 256, 0, stream>>>(ACC, Wot, b_out, (float*)d_out, Nn);
}

// Round 21
// 440.914 us; speedup vs baseline: 1.2043x; 1.0823x over previous
//
#include <hip/hip_runtime.h>
#include <hip/hip_bf16.h>
#include <cstdint>
#include <cstddef>

// GraphAttentionLayer: N=30000, E=480000, C=128, H=8, DH=16, NB=32, NA=16, FC=64.
//
// R21 == R20 resubmission (R20 died on infra: UnresponsiveContainer; never ran).
// R20 = REVERT to R16 (best measured: 442.8us total, msg_attn 307us) + R18's
// independent 4-deep aggregate unroll.
// Evidence base: R17 (fewer barriers) null; R18 (TILE-32, occ 89%) spilled;
// R19 (TILE-32, occ 66%, no spill) still +40us from 2x weight traffic.
// => TILE-64 / bound(256,4) / short-range prefetch is the local optimum.

typedef unsigned short u16;
typedef unsigned int u32;
typedef __attribute__((ext_vector_type(8))) short bf16x8;
typedef __attribute__((ext_vector_type(4))) float f32x4;

union fu_ { float f; u32 u; };
static __device__ __forceinline__ float lo2f(u32 v) { fu_ x; x.u = v << 16; return x.f; }
static __device__ __forceinline__ float hi2f(u32 v) { fu_ x; x.u = v & 0xFFFF0000u; return x.f; }
static __device__ __forceinline__ u16 f2bf(float f) {
    union { __hip_bfloat16 h; u16 u; } c;
    c.h = __float2bfloat16(f);
    return c.u;
}
static __device__ __forceinline__ u32 pack2(float a, float b) {
    return (u32)f2bf(a) | ((u32)f2bf(b) << 16);
}
static __device__ __forceinline__ float sigmoidf_(float x) { return 1.0f / (1.0f + __expf(-x)); }
static __device__ __forceinline__ float siluf_(float x)    { return x * sigmoidf_(x); }
static __device__ __forceinline__ float slreluf_(float x)  { return x * (0.2f + 0.8f * sigmoidf_(x)); }

#define MFMA16(a, b, c) __builtin_amdgcn_mfma_f32_16x16x32_bf16((a), (b), (c), 0, 0, 0)

static __device__ __forceinline__ bf16x8 ld8f_bf(const float* __restrict__ p) {
    const float4 x = *reinterpret_cast<const float4*>(p);
    const float4 y = *reinterpret_cast<const float4*>(p + 4);
    bf16x8 r;
    r[0] = (short)f2bf(x.x); r[1] = (short)f2bf(x.y);
    r[2] = (short)f2bf(x.z); r[3] = (short)f2bf(x.w);
    r[4] = (short)f2bf(y.x); r[5] = (short)f2bf(y.y);
    r[6] = (short)f2bf(y.z); r[7] = (short)f2bf(y.w);
    return r;
}

// bijective XCD swizzle (m204)
static __device__ __forceinline__ int xcd_swz(int orig, int nwg) {
    const int q = nwg >> 3, rr = nwg & 7;
    const int xcd = orig & 7, idx = orig >> 3;
    return (xcd < rr ? xcd * (q + 1) : rr * (q + 1) + (xcd - rr) * q) + idx;
}

// ---------------- CSR build ----------------
__global__ void hist_k(const int* __restrict__ dst, int* __restrict__ deg, int E) {
    int i = blockIdx.x * blockDim.x + threadIdx.x;
    if (i < E) atomicAdd(&deg[dst[i]], 1);
}

__global__ void scan_k(const int* __restrict__ deg, int* __restrict__ rowptr,
                       int* __restrict__ cursor, int n) {
    __shared__ int part[1024];
    const int t = threadIdx.x;
    const int C = (n + 1023) / 1024;
    const int lo = t * C;
    const int hi = (lo + C < n) ? (lo + C) : n;
    int s = 0;
    for (int i = lo; i < hi; ++i) s += deg[i];
    part[t] = s;
    __syncthreads();
    for (int off = 1; off < 1024; off <<= 1) {
        int v = part[t];
        int u = (t >= off) ? part[t - off] : 0;
        __syncthreads();
        part[t] = v + u;
        __syncthreads();
    }
    int excl = (t == 0) ? 0 : part[t - 1];
    for (int i = lo; i < hi; ++i) {
        rowptr[i] = excl;
        cursor[i] = excl;
        excl += deg[i];
    }
    if (t == 1023) rowptr[n] = part[1023];
}

__global__ void fill_k(const int* __restrict__ dst, int* __restrict__ cursor,
                       int* __restrict__ eids, int E) {
    int i = blockIdx.x * blockDim.x + threadIdx.x;
    if (i < E) {
        int d = dst[i];
        int p = atomicAdd(&cursor[d], 1);
        eids[p] = i;
    }
}

// ---------------- weight prep (all transposed, bf16) ----------------
__global__ void prep_w_k(const float* __restrict__ Wa, const float* __restrict__ Wl,
                         const float* __restrict__ Wv,
                         const float* __restrict__ W1, const float* __restrict__ W2,
                         const float* __restrict__ W3,
                         const float* __restrict__ Wsrc, const float* __restrict__ Wdst,
                         const float* __restrict__ Wout,
                         u16* __restrict__ Wct, u16* __restrict__ Wvt,
                         u16* __restrict__ Bt1, u16* __restrict__ Bt2,
                         u16* __restrict__ Bt3,
                         u16* __restrict__ Wst, u16* __restrict__ Wdt,
                         u16* __restrict__ Wot) {
    int idx = blockIdx.x * 256 + threadIdx.x;
    if (idx < 32768) {
        int c = idx >> 7, k = idx & 127;
        float v = (c < 128) ? Wa[(size_t)k * 128 + c] : Wl[(size_t)k * 128 + (c - 128)];
        Wct[idx] = f2bf(v);
    } else if (idx < 49152) {
        int t = idx - 32768;
        int j = t >> 7, c = t & 127;
        Wvt[t] = f2bf(Wv[(size_t)c * 128 + j]);
    } else if (idx < 53248) {
        int t = idx - 49152;
        int c = t >> 6, k = t & 63;
        Bt1[t] = f2bf(W1[(size_t)k * 64 + c]);
    } else if (idx < 57344) {
        int t = idx - 53248;
        int c = t >> 6, k = t & 63;
        Bt2[t] = f2bf(W2[(size_t)k * 64 + c]);
    } else if (idx < 65536) {
        int t = idx - 57344;
        int c = t >> 6, k = t & 63;
        Bt3[t] = f2bf(W3[(size_t)k * 128 + c]);
    } else if (idx < 81920) {
        int t = idx - 65536;
        int c = t >> 7, k = t & 127;
        Wst[t] = f2bf(Wsrc[(size_t)k * 128 + c]);
    } else if (idx < 98304) {
        int t = idx - 81920;
        int c = t >> 7, k = t & 127;
        Wdt[t] = f2bf(Wdst[(size_t)k * 128 + c]);
    } else if (idx < 114688) {
        int t = idx - 98304;
        int c = t >> 7, k = t & 127;
        Wot[t] = f2bf(Wout[(size_t)k * 128 + c]);
    }
}

// ---------------- dual node projection: Psrc,Pdst (bf16 out) in one pass ----------------
__global__ __launch_bounds__(256) void proj2_mfma_k(const float* __restrict__ A,
                                                    const u16* __restrict__ Wt1,
                                                    const u16* __restrict__ Wt2,
                                                    const float* __restrict__ bias1,
                                                    u16* __restrict__ O1,
                                                    u16* __restrict__ O2, int M) {
    const int tid  = threadIdx.x;
    const int lane = tid & 63;
    const int w    = tid >> 6;
    const int lr   = lane & 15;
    const int lg   = lane >> 4;
    const int e0   = blockIdx.x * 64;

    f32x4 acc1[4][2], acc2[4][2];
#pragma unroll
    for (int m = 0; m < 4; ++m)
#pragma unroll
        for (int n = 0; n < 2; ++n) { acc1[m][n] = (f32x4)(0.0f); acc2[m][n] = (f32x4)(0.0f); }

#pragma unroll
    for (int ks = 0; ks < 4; ++ks) {
        const int kk = lg * 8 + ks * 32;
        bf16x8 a[4], b1v[2], b2v[2];
#pragma unroll
        for (int m = 0; m < 4; ++m) {
            int row = e0 + lr + 16 * m;
            row = (row < M) ? row : (M - 1);
            a[m] = ld8f_bf(&A[(size_t)row * 128 + kk]);
        }
#pragma unroll
        for (int n = 0; n < 2; ++n) {
            const int c = 32 * w + 16 * n + lr;
            b1v[n] = *reinterpret_cast<const bf16x8*>(&Wt1[(size_t)c * 128 + kk]);
            b2v[n] = *reinterpret_cast<const bf16x8*>(&Wt2[(size_t)c * 128 + kk]);
        }
#pragma unroll
        for (int m = 0; m < 4; ++m)
#pragma unroll
            for (int n = 0; n < 2; ++n) {
                acc1[m][n] = MFMA16(a[m], b1v[n], acc1[m][n]);
                acc2[m][n] = MFMA16(a[m], b2v[n], acc2[m][n]);
            }
    }

#pragma unroll
    for (int n = 0; n < 2; ++n) {
        const int j = 32 * w + 16 * n + lr;
        const float bv = bias1[j];
#pragma unroll
        for (int m = 0; m < 4; ++m)
#pragma unroll
            for (int i = 0; i < 4; ++i) {
                const int row = e0 + 16 * m + 4 * lg + i;
                if (row < M) {
                    O1[(size_t)row * 128 + j] = f2bf(acc1[m][n][i] + bv);
                    O2[(size_t)row * 128 + j] = f2bf(acc2[m][n][i]);
                }
            }
    }
}

// ---------------- fused radial MLP + message + attention + value ----------------
// R16 structure: TILE=64, column-split, short-range prefetch across fc3 only.
__global__ __launch_bounds__(256, 4) void msg_attn_k(
    const float* __restrict__ eemb, const float* __restrict__ nattr,
    const float* __restrict__ ea,
    const int* __restrict__ src, const int* __restrict__ dst,
    const int* __restrict__ eids,
    const u16* __restrict__ Bt1, const float* __restrict__ b1,
    const u16* __restrict__ Bt2, const float* __restrict__ b2,
    const u16* __restrict__ Bt3,
    const u16* __restrict__ Ps, const u16* __restrict__ Pd,
    const u16* __restrict__ Wct, const u16* __restrict__ Wvt,
    const float* __restrict__ att_dot, const float* __restrict__ w_int,
    float* __restrict__ LG, u16* __restrict__ V, int E) {
    __shared__ __align__(16) char smem[35840];
    char* regA   = smem;                    // H1s [0,8K) + H2s [8K,16K); later V1s
    char* regB   = smem + 16384;            // Wts -> MSGs (in place) -> Vout
    float* lgs   = (float*)(smem + 32768);  // 64*8 f32
    int*   eid_l = (int*)(smem + 34816);    // [64]
    int*   src_l = eid_l + 64;
    int*   dst_l = src_l + 64;
    float* ea_l  = (float*)(dst_l + 64);

    const int tid  = threadIdx.x;
    const int lane = tid & 63;
    const int w    = tid >> 6;
    const int lr   = lane & 15;
    const int lg   = lane >> 4;
    const int e0   = xcd_swz(blockIdx.x, gridDim.x) * 64;  // CSR slot base

    // ---- phase 0: stage slot->edge metadata ----
    if (tid < 64) {
        int slot = e0 + tid;
        int e = (slot < E) ? eids[slot] : eids[E - 1];
        eid_l[tid] = e;
        src_l[tid] = src[e];
        dst_l[tid] = dst[e];
        ea_l[tid]  = ea[e];
    }
    __syncthreads();

    // ---- phase 1: fc1  H1 = silu(WF @ W1 + b1), A gathered via eid ----
    {
        f32x4 acc1[4];
#pragma unroll
        for (int m = 0; m < 4; ++m) acc1[m] = (f32x4)(0.0f);
#pragma unroll
        for (int ks = 0; ks < 2; ++ks) {
            const int kk = lg * 8 + ks * 32;
            bf16x8 a[4];
#pragma unroll
            for (int m = 0; m < 4; ++m) {
                const int r = lr + 16 * m;
                const float* ap;
                if (kk < 32)      ap = &eemb[(size_t)eid_l[r] * 32 + kk];
                else if (kk < 48) ap = &nattr[(size_t)src_l[r] * 16 + (kk - 32)];
                else              ap = &nattr[(size_t)dst_l[r] * 16 + (kk - 48)];
                a[m] = ld8f_bf(ap);
            }
            const bf16x8 b = *reinterpret_cast<const bf16x8*>(&Bt1[(size_t)(16 * w + lr) * 64 + kk]);
#pragma unroll
            for (int m = 0; m < 4; ++m) acc1[m] = MFMA16(a[m], b, acc1[m]);
        }
        const int c = 16 * w + lr;
        const float bias = b1[c];
#pragma unroll
        for (int m = 0; m < 4; ++m)
#pragma unroll
            for (int i = 0; i < 4; ++i) {
                const int r = 16 * m + 4 * lg + i;
                const int byte = (r * 128 + c * 2) ^ ((r & 7) << 4);
                *reinterpret_cast<u16*>(regA + byte) = f2bf(siluf_(acc1[m][i] + bias));
            }
    }
    __syncthreads();

    // ---- phase 2: fc2  H2 = silu(H1 @ W2 + b2) ----
    {
        f32x4 acc2[4];
#pragma unroll
        for (int m = 0; m < 4; ++m) acc2[m] = (f32x4)(0.0f);
#pragma unroll
        for (int ks = 0; ks < 2; ++ks) {
            const int kk = lg * 8 + ks * 32;
            bf16x8 a[4];
#pragma unroll
            for (int m = 0; m < 4; ++m) {
                const int r = lr + 16 * m;
                const int byte = (r * 128 + kk * 2) ^ ((r & 7) << 4);
                a[m] = *reinterpret_cast<const bf16x8*>(regA + byte);
            }
            const bf16x8 b = *reinterpret_cast<const bf16x8*>(&Bt2[(size_t)(16 * w + lr) * 64 + kk]);
#pragma unroll
            for (int m = 0; m < 4; ++m) acc2[m] = MFMA16(a[m], b, acc2[m]);
        }
        const int c = 16 * w + lr;
        const float bias = b2[c];
#pragma unroll
        for (int m = 0; m < 4; ++m)
#pragma unroll
            for (int i = 0; i < 4; ++i) {
                const int r = 16 * m + 4 * lg + i;
                const int byte = (r * 128 + c * 2) ^ ((r & 7) << 4);
                *reinterpret_cast<u16*>(regA + 8192 + byte) = f2bf(siluf_(acc2[m][i] + bias));
            }
    }
    __syncthreads();

    // ---- prefetch (short range): issue Ps/Pd gathers; consume in phase 4 ----
    uint4 psv_r[4], pdv_r[4];
    {
        const int c8p = (tid & 15) * 8;
#pragma unroll
        for (int t = 0; t < 4; ++t) {
            const int r = (tid >> 4) + 16 * t;
            psv_r[t] = *reinterpret_cast<const uint4*>(&Ps[(size_t)src_l[r] * 128 + c8p]);
            pdv_r[t] = *reinterpret_cast<const uint4*>(&Pd[(size_t)dst_l[r] * 128 + c8p]);
        }
    }

    // ---- phase 3: fc3  W = H2 @ W3 -> Wts (regB) ----
    {
        f32x4 acc3[2][4];
#pragma unroll
        for (int n = 0; n < 2; ++n)
#pragma unroll
            for (int m = 0; m < 4; ++m) acc3[n][m] = (f32x4)(0.0f);
#pragma unroll
        for (int ks = 0; ks < 2; ++ks) {
            const int kk = lg * 8 + ks * 32;
            bf16x8 a[4];
#pragma unroll
            for (int m = 0; m < 4; ++m) {
                const int r = lr + 16 * m;
                const int byte = (r * 128 + kk * 2) ^ ((r & 7) << 4);
                a[m] = *reinterpret_cast<const bf16x8*>(regA + 8192 + byte);
            }
            bf16x8 b[2];
#pragma unroll
            for (int n = 0; n < 2; ++n) {
                const int c = 32 * w + 16 * n + lr;
                b[n] = *reinterpret_cast<const bf16x8*>(&Bt3[(size_t)c * 64 + kk]);
            }
#pragma unroll
            for (int n = 0; n < 2; ++n)
#pragma unroll
                for (int m = 0; m < 4; ++m) acc3[n][m] = MFMA16(a[m], b[n], acc3[n][m]);
        }
#pragma unroll
        for (int n = 0; n < 2; ++n) {
            const int c = 32 * w + 16 * n + lr;
#pragma unroll
            for (int m = 0; m < 4; ++m)
#pragma unroll
                for (int i = 0; i < 4; ++i) {
                    const int r = 16 * m + 4 * lg + i;
                    const int byte = (r * 256 + c * 2) ^ ((r & 7) << 4);
                    *reinterpret_cast<u16*>(regB + byte) = f2bf(acc3[n][m][i]);
                }
        }
    }
    __syncthreads();

    // ---- phase 4: epilogue IN PLACE on regB; Ps/Pd from prefetch registers ----
#pragma unroll
    for (int t = 0; t < 4; ++t) {
        const int idx = tid + 256 * t;
        const int r = idx >> 4;
        const int c8 = (idx & 15) * 8;
        if (e0 + r >= E) continue;
        const int byte = (r * 256 + c8 * 2) ^ ((r & 7) << 4);
        const uint4 wv = *reinterpret_cast<const uint4*>(regB + byte);
        const float wt[8] = {lo2f(wv.x), hi2f(wv.x), lo2f(wv.y), hi2f(wv.y),
                             lo2f(wv.z), hi2f(wv.z), lo2f(wv.w), hi2f(wv.w)};
        const float eav = ea_l[r];
        const uint4 psv = psv_r[t];
        const uint4 pdv = pdv_r[t];
        const float ps[8] = {lo2f(psv.x), hi2f(psv.x), lo2f(psv.y), hi2f(psv.y),
                             lo2f(psv.z), hi2f(psv.z), lo2f(psv.w), hi2f(psv.w)};
        const float pd[8] = {lo2f(pdv.x), hi2f(pdv.x), lo2f(pdv.y), hi2f(pdv.y),
                             lo2f(pdv.z), hi2f(pdv.z), lo2f(pdv.w), hi2f(pdv.w)};
        float m[8];
#pragma unroll
        for (int j = 0; j < 8; ++j) m[j] = (ps[j] + pd[j]) * eav * wt[j];
        u32 p0 = pack2(m[0], m[1]), p1 = pack2(m[2], m[3]);
        u32 p2 = pack2(m[4], m[5]), p3 = pack2(m[6], m[7]);
        *reinterpret_cast<uint4*>(regB + byte) = make_uint4(p0, p1, p2, p3);
    }
    __syncthreads();

    // ---- phase 5+6 fused, per-n: GEMM1 fragment -> immediate consume ----
    const int c0w = w * 64;
#pragma unroll
    for (int n = 0; n < 4; ++n) {
        f32x4 accn[4];
#pragma unroll
        for (int m = 0; m < 4; ++m) accn[m] = (f32x4)(0.0f);
#pragma unroll
        for (int ks = 0; ks < 4; ++ks) {
            const int kk = lg * 8 + ks * 32;
            const bf16x8 b = *reinterpret_cast<const bf16x8*>(
                &Wct[(size_t)(c0w + 16 * n + lr) * 128 + kk]);
#pragma unroll
            for (int m = 0; m < 4; ++m) {
                const int r = lr + 16 * m;
                const int byte = (r * 256 + kk * 2) ^ ((r & 7) << 4);
                const bf16x8 am = *reinterpret_cast<const bf16x8*>(regB + byte);
                accn[m] = MFMA16(am, b, accn[m]);
            }
        }
        if (w < 2) {
            const float ad = att_dot[c0w + 16 * n + lr];
            const int h = 4 * w + n;
#pragma unroll
            for (int m = 0; m < 4; ++m) {
#pragma unroll
                for (int i = 0; i < 4; ++i) {
                    float s = slreluf_(accn[m][i]) * ad;
                    s += __shfl_xor(s, 1);
                    s += __shfl_xor(s, 2);
                    s += __shfl_xor(s, 4);
                    s += __shfl_xor(s, 8);
                    if (lr == 0) lgs[(16 * m + 4 * lg + i) * 8 + h] = s;
                }
            }
        } else {
            const int cc = 64 * (w - 2) + 16 * n + lr;
            const float wi = w_int[cc];
#pragma unroll
            for (int m = 0; m < 4; ++m) {
#pragma unroll
                for (int i = 0; i < 4; ++i) {
                    const int r = 16 * m + 4 * lg + i;
                    const float v1 = siluf_(accn[m][i]) * ea_l[r] * wi;
                    const int byte = (r * 256 + cc * 2) ^ ((r & 7) << 4);
                    *reinterpret_cast<u16*>(regA + byte) = f2bf(v1);
                }
            }
        }
    }
    __syncthreads();  // V1 complete; all GEMM1 reads of regB done

    // ---- phase 7: GEMM2  V = V1 @ Wv; Vout -> regB ----
    {
        f32x4 acc2[4][2];
#pragma unroll
        for (int m = 0; m < 4; ++m)
#pragma unroll
            for (int n = 0; n < 2; ++n) acc2[m][n] = (f32x4)(0.0f);
#pragma unroll
        for (int ks = 0; ks < 4; ++ks) {
            const int kk = lg * 8 + ks * 32;
            bf16x8 a2[4], b2[2];
#pragma unroll
            for (int m = 0; m < 4; ++m) {
                const int r = lr + 16 * m;
                const int byte = (r * 256 + kk * 2) ^ ((r & 7) << 4);
                a2[m] = *reinterpret_cast<const bf16x8*>(regA + byte);
            }
#pragma unroll
            for (int n = 0; n < 2; ++n) {
                const int j = 32 * w + 16 * n + lr;
                b2[n] = *reinterpret_cast<const bf16x8*>(&Wvt[(size_t)j * 128 + kk]);
            }
#pragma unroll
            for (int m = 0; m < 4; ++m)
#pragma unroll
                for (int n = 0; n < 2; ++n) acc2[m][n] = MFMA16(a2[m], b2[n], acc2[m][n]);
        }
        u16* Vout = (u16*)regB;
#pragma unroll
        for (int n = 0; n < 2; ++n) {
            const int j = 32 * w + 16 * n + lr;
#pragma unroll
            for (int m = 0; m < 4; ++m)
#pragma unroll
                for (int i = 0; i < 4; ++i) {
                    const int r = 16 * m + 4 * lg + i;
                    Vout[r * 128 + j] = f2bf(acc2[m][n][i]);
                }
        }
    }
    __syncthreads();

    // ---- phase 8: fully sequential writeout (slot order) ----
    const uint4* vo = reinterpret_cast<const uint4*>(regB);
#pragma unroll
    for (int t = 0; t < 4; ++t) {
        const int idx = tid + 256 * t;
        const int row = idx >> 4;
        if (e0 + row < E)
            *reinterpret_cast<uint4*>(&V[(size_t)e0 * 128 + idx * 8]) = vo[idx];
    }
    if (tid < 128) {
        const int row = tid >> 1;
        if (e0 + row < E)
            *reinterpret_cast<float4*>(&LG[(size_t)e0 * 8 + tid * 4]) =
                *reinterpret_cast<const float4*>(&lgs[tid * 4]);
    }
}

// ---------------- CSR aggregation (wave-per-node), bf16 ACC out ----------------
__global__ __launch_bounds__(256) void aggregate_k(const int* __restrict__ rowptr,
                                                   const float* __restrict__ LG,
                                                   const u16* __restrict__ V,
                                                   u16* __restrict__ ACC, int Nn) {
    const int node = blockIdx.x * 4 + (threadIdx.x >> 6);
    const int lane = threadIdx.x & 63;
    if (node >= Nn) return;
    const int s = rowptr[node], t = rowptr[node + 1];
    const int h = lane >> 3;
    float a0 = 0.0f, a1 = 0.0f, ds = 0.0f;
    int i = s;
    for (; i + 3 < t; i += 4) {  // 4-deep unroll: 4 loads in flight
        float ex[4];
        u32 vv[4];
#pragma unroll
        for (int u = 0; u < 4; ++u) {
            ex[u] = __expf(LG[(size_t)(i + u) * 8 + h]);
            vv[u] = *reinterpret_cast<const u32*>(&V[(size_t)(i + u) * 128 + lane * 2]);
        }
#pragma unroll
        for (int u = 0; u < 4; ++u) {
            a0 += ex[u] * lo2f(vv[u]);
            a1 += ex[u] * hi2f(vv[u]);
            ds += ex[u];
        }
    }
    for (; i < t; ++i) {
        const float ex0 = __expf(LG[(size_t)i * 8 + h]);
        const u32 v0 = *reinterpret_cast<const u32*>(&V[(size_t)i * 128 + lane * 2]);
        a0 += ex0 * lo2f(v0);
        a1 += ex0 * hi2f(v0);
        ds += ex0;
    }
    const float inv = 1.0f / (ds + 1e-16f);
    *reinterpret_cast<u32*>(&ACC[(size_t)node * 128 + lane * 2]) = pack2(a0 * inv, a1 * inv);
}

// ---------------- output projection from bf16 ACC ----------------
__global__ __launch_bounds__(256) void outproj_mfma_k(const u16* __restrict__ A,
                                                      const u16* __restrict__ Wt,
                                                      const float* __restrict__ bias,
                                                      float* __restrict__ Out, int M) {
    const int tid  = threadIdx.x;
    const int lane = tid & 63;
    const int w    = tid >> 6;
    const int lr   = lane & 15;
    const int lg   = lane >> 4;
    const int e0   = blockIdx.x * 64;

    f32x4 acc[4][2];
#pragma unroll
    for (int m = 0; m < 4; ++m)
#pragma unroll
        for (int n = 0; n < 2; ++n) acc[m][n] = (f32x4)(0.0f);

#pragma unroll
    for (int ks = 0; ks < 4; ++ks) {
        const int kk = lg * 8 + ks * 32;
        bf16x8 a[4], b[2];
#pragma unroll
        for (int m = 0; m < 4; ++m) {
            int row = e0 + lr + 16 * m;
            row = (row < M) ? row : (M - 1);
            a[m] = *reinterpret_cast<const bf16x8*>(&A[(size_t)row * 128 + kk]);
        }
#pragma unroll
        for (int n = 0; n < 2; ++n) {
            const int c = 32 * w + 16 * n + lr;
            b[n] = *reinterpret_cast<const bf16x8*>(&Wt[(size_t)c * 128 + kk]);
        }
#pragma unroll
        for (int m = 0; m < 4; ++m)
#pragma unroll
            for (int n = 0; n < 2; ++n) acc[m][n] = MFMA16(a[m], b[n], acc[m][n]);
    }

#pragma unroll
    for (int n = 0; n < 2; ++n) {
        const int j = 32 * w + 16 * n + lr;
        const float bv = bias[j];
#pragma unroll
        for (int m = 0; m < 4; ++m)
#pragma unroll
            for (int i = 0; i < 4; ++i) {
                const int row = e0 + 16 * m + 4 * lg + i;
                if (row < M) Out[(size_t)row * 128 + j] = acc[m][n][i] + bv;
            }
    }
}

// ---------------- launch ----------------
extern "C" void kernel_launch(void* const* d_in, const int* in_sizes, int n_in,
                              void* d_out, int out_size, void* d_ws, size_t ws_size,
                              hipStream_t stream) {
    const float* node_feats = (const float*)d_in[0];
    const float* node_attr  = (const float*)d_in[1];
    const float* edge_attr  = (const float*)d_in[2];
    const float* edge_emb   = (const float*)d_in[3];
    const float* W_src      = (const float*)d_in[4];
    const float* b_src      = (const float*)d_in[5];
    const float* W_dst      = (const float*)d_in[6];
    const float* W_fc1      = (const float*)d_in[7];
    const float* b_fc1      = (const float*)d_in[8];
    const float* W_fc2      = (const float*)d_in[9];
    const float* b_fc2      = (const float*)d_in[10];
    const float* W_fc3      = (const float*)d_in[11];
    const float* W_alpha    = (const float*)d_in[12];
    const float* W_lin      = (const float*)d_in[13];
    const float* w_int      = (const float*)d_in[14];
    const float* W_val      = (const float*)d_in[15];
    const float* att_dot    = (const float*)d_in[16];
    const float* W_out      = (const float*)d_in[17];
    const float* b_out      = (const float*)d_in[18];
    const int* esrc         = (const int*)d_in[19];
    const int* edst         = (const int*)d_in[20];

    const int Nn = in_sizes[0] / 128;  // 30000
    const int E  = in_sizes[19];       // 480000

    char* w = (char*)d_ws;
    auto alloc = [&](size_t bytes) {
        char* p = w;
        w += (bytes + 255) & ~(size_t)255;
        return p;
    };
    u16* V      = (u16*)alloc((size_t)E * 128 * 2);    // CSR-ordered
    float* LG   = (float*)alloc((size_t)E * 8 * 4);    // CSR-ordered
    u16* Psrc   = (u16*)alloc((size_t)Nn * 128 * 2);   // bf16
    u16* Pdst   = (u16*)alloc((size_t)Nn * 128 * 2);   // bf16
    u16* ACC    = (u16*)alloc((size_t)Nn * 128 * 2);   // bf16
    int* deg    = (int*)alloc((size_t)Nn * 4);
    int* rowptr = (int*)alloc((size_t)(Nn + 1) * 4);
    int* cursor = (int*)alloc((size_t)Nn * 4);
    int* eids   = (int*)alloc((size_t)E * 4);
    u16* Wct    = (u16*)alloc(32768 * 2);
    u16* Wvt    = (u16*)alloc(16384 * 2);
    u16* Bt1    = (u16*)alloc(4096 * 2);
    u16* Bt2    = (u16*)alloc(4096 * 2);
    u16* Bt3    = (u16*)alloc(8192 * 2);
    u16* Wst    = (u16*)alloc(16384 * 2);
    u16* Wdt    = (u16*)alloc(16384 * 2);
    u16* Wot    = (u16*)alloc(16384 * 2);

    // CSR build + weight prep
    hipMemsetAsync(deg, 0, (size_t)Nn * 4, stream);
    hist_k<<<(E + 255) / 256, 256, 0, stream>>>(edst, deg, E);
    scan_k<<<1, 1024, 0, stream>>>(deg, rowptr, cursor, Nn);
    fill_k<<<(E + 255) / 256, 256, 0, stream>>>(edst, cursor, eids, E);
    prep_w_k<<<448, 256, 0, stream>>>(W_alpha, W_lin, W_val, W_fc1, W_fc2, W_fc3,
                                      W_src, W_dst, W_out,
                                      Wct, Wvt, Bt1, Bt2, Bt3, Wst, Wdt, Wot);

    const int nb_node = (Nn + 63) / 64;  // 469
    const int nb_e    = (E + 63) / 64;   // 7500

    proj2_mfma_k<<<nb_node, 256, 0, stream>>>(node_feats, Wst, Wdt, b_src, Psrc, Pdst, Nn);

    msg_attn_k<<<nb_e, 256, 0, stream>>>(edge_emb, node_attr, edge_attr, esrc, edst, eids,
                                         Bt1, b_fc1, Bt2, b_fc2, Bt3,
                                         Psrc, Pdst, Wct, Wvt, att_dot, w_int,
                                         LG, V, E);

    aggregate_k<<<(Nn + 3) / 4, 256, 0, stream>>>(rowptr, LG, V, ACC, Nn);

    outproj_mfma_k<<<nb_node, 256, 0, stream>>>(ACC, Wot, b_out, (float*)d_out, Nn);
}